// Round 8
// baseline (445.002 us; speedup 1.0000x reference)
//
#include <hip/hip_runtime.h>
#include <hip/hip_bf16.h>
#include <hip/hip_fp16.h>

#define NN 20000   // nodes
#define FD 512     // features
#define NH 8       // heads
#define NE 320000  // edges
#define MP 20096   // padded rows = 157*128

typedef unsigned int u32;
typedef unsigned short u16;
typedef __bf16 bf16x8 __attribute__((ext_vector_type(8)));
typedef _Float16 f16x8 __attribute__((ext_vector_type(8)));
typedef float f32x4 __attribute__((ext_vector_type(4)));

#define AS1 __attribute__((address_space(1)))
#define AS3 __attribute__((address_space(3)))

__device__ __forceinline__ u16 f2bf(float f) {
  __hip_bfloat16 h = __float2bfloat16(f);
  union { __hip_bfloat16 b; u16 u; } c; c.b = h; return c.u;
}
__device__ __forceinline__ float bf2f(u32 u) { return __uint_as_float(u << 16); }
__device__ __forceinline__ u16 f2h(float f) {
  union { __half h; u16 u; } c; c.h = __float2half(f); return c.u;
}
__device__ __forceinline__ void gl_lds16(const void* g, void* l) {
  __builtin_amdgcn_global_load_lds((AS1 void*)const_cast<void*>(g), (AS3 void*)l, 16, 0, 0);
}
__device__ __forceinline__ void up_h4(uint2 w, float* f) {
  union { u32 u; __half2 h; } c;
  c.u = w.x; float2 t0 = __half22float2(c.h); f[0]=t0.x; f[1]=t0.y;
  c.u = w.y; float2 t1 = __half22float2(c.h); f[2]=t1.x; f[3]=t1.y;
}

// ---- feat->fp16 + all weight prep + degree histogram in ONE kernel ----
__global__ __launch_bounds__(256) void k_wprep(const float* __restrict__ feat,
    const float* __restrict__ Wq, const float* __restrict__ Wk,
    const float* __restrict__ Wv, const float* __restrict__ Wsk,
    const float* __restrict__ Wn, const float* __restrict__ W1,
    const float* __restrict__ W2, const float* __restrict__ Wg,
    const int* __restrict__ e_dst,
    u16* __restrict__ Af, u16* __restrict__ Bqkvs, u16* __restrict__ Bnt,
    u16* __restrict__ B1t, u16* __restrict__ B2t,
    float* __restrict__ gA, float* __restrict__ gB, int* __restrict__ deg)
{
  int idx = blockIdx.x * 256 + threadIdx.x;
  if (idx < MP * FD / 4) {
    size_t i = (size_t)idx * 4;
    float4 v = make_float4(0.f, 0.f, 0.f, 0.f);
    if (i < (size_t)NN * FD) v = *(const float4*)(feat + i);
    *(ushort4*)(Af + i) = make_ushort4(f2h(v.x), f2h(v.y), f2h(v.z), f2h(v.w));
    return;
  }
  idx -= MP * FD / 4;
  if (idx < 2048 * 512) {
    int n = idx >> 9, k = idx & 511;
    float v;
    if (n < 512)       v = Wq[k * 512 + n];
    else if (n < 1024) v = Wk[k * 512 + (n - 512)];
    else if (n < 1536) v = Wv[k * 512 + (n - 1024)];
    else               v = Wsk[k * 512 + (n - 1536)];
    Bqkvs[idx] = f2h(v);
    return;
  }
  idx -= 2048 * 512;
  if (idx < 512 * 512) { int n = idx >> 9, k = idx & 511; Bnt[idx] = f2bf(Wn[k * 512 + n]); return; }
  idx -= 512 * 512;
  if (idx < 512 * 512) { int n = idx >> 9, k = idx & 511; B1t[idx] = f2bf(W1[k * 512 + n]); return; }
  idx -= 512 * 512;
  if (idx < 512 * 512) { int n = idx >> 9, k = idx & 511; B2t[idx] = f2bf(W2[k * 512 + n]); return; }
  idx -= 512 * 512;
  if (idx < 512) {
    gA[idx] = Wg[idx] + Wg[2 * 512 + idx];
    gB[idx] = Wg[512 + idx] - Wg[2 * 512 + idx];
    return;
  }
  idx -= 512;
  if (idx < NE) atomicAdd(&deg[e_dst[idx]], 1);
}

// ---- GEMM: A[M,512] x Bt[NCOLS,512] (both u16-encoded, FP16 or bf16) ----
// BK=32 double-buffer (1 barrier/K-step, prefetch in flight across MFMA phase).
// BN=128: 32 KB LDS, 4 blocks/CU.  BN=256 (QKVS): 48 KB LDS, 3 blocks/CU,
// 32 MFMA/barrier.  Grid.x padded to 160 so XCD = row%8 (A-panel L2 affinity).
// MODE: 1=relu+bf16->Cb, 2=bf16->Cb,
//       6=QKVS split store: col<512 q->Cb(QV,stride1024 fp16); <1024 k->Cb2(fp16);
//                           <1536 v->Cb(QV+512 fp16); else skip->Cb3(bf16)
//       7=h+ffn: Cf[o] = bf2f(Cb2[o]) + v   (writes d_out once)
template<int NCOLS, int MODE, int FP16, int BN>
__global__ __launch_bounds__(256, (BN == 256) ? 3 : 4) void k_gemm(
    const u16* __restrict__ A, const u16* __restrict__ B,
    float* __restrict__ Cf, u16* __restrict__ Cb, u16* __restrict__ Cb2,
    u16* __restrict__ Cb3, int Mreal)
{
  constexpr int NF = BN / 32;   // col frags per wave
  const long brow = (long)blockIdx.x * 128;
  if (brow >= MP) return;
  __shared__ u16 sA[2][128 * 32];
  __shared__ u16 sB[2][BN * 32];
  const int tid = threadIdx.x, lane = tid & 63, w = tid >> 6;
  const int wr = w >> 1, wc = w & 1;
  const long bcol = (long)blockIdx.y * BN;
  const int srl = tid >> 2, scl = (tid & 3) * 8;

  auto stage = [&](int b, int kt) {
#pragma unroll
    for (int s = 0; s < 2; s++)
      gl_lds16(A + (brow + s * 64 + srl) * FD + kt + scl, &sA[b][s * 2048 + w * 512]);
#pragma unroll
    for (int s = 0; s < BN / 64; s++)
      gl_lds16(B + (bcol + s * 64 + srl) * FD + kt + scl, &sB[b][s * 2048 + w * 512]);
  };

  f32x4 acc[4][NF] = {};
  stage(0, 0);
  __syncthreads();
  int cur = 0;
  const int ro = (lane >> 4) * 8;
  for (int kt = 0; kt < FD; kt += 32) {
    if (kt + 32 < FD) stage(cur ^ 1, kt + 32);
#pragma unroll
    for (int m = 0; m < 4; m++) {
      const u16* pa = &sA[cur][(wr * 64 + m * 16 + (lane & 15)) * 32 + ro];
#pragma unroll
      for (int n = 0; n < NF; n++) {
        const u16* pb = &sB[cur][(wc * (BN / 2) + n * 16 + (lane & 15)) * 32 + ro];
        if constexpr (FP16)
          acc[m][n] = __builtin_amdgcn_mfma_f32_16x16x32_f16(
              *(const f16x8*)pa, *(const f16x8*)pb, acc[m][n], 0, 0, 0);
        else
          acc[m][n] = __builtin_amdgcn_mfma_f32_16x16x32_bf16(
              *(const bf16x8*)pa, *(const bf16x8*)pb, acc[m][n], 0, 0, 0);
      }
    }
    __syncthreads();
    cur ^= 1;
  }
#pragma unroll
  for (int m = 0; m < 4; m++) {
    long row0 = brow + wr * 64 + m * 16 + (lane >> 4) * 4;
#pragma unroll
    for (int n = 0; n < NF; n++) {
      long col = bcol + wc * (BN / 2) + n * 16 + (lane & 15);
#pragma unroll
      for (int j = 0; j < 4; j++) {
        long row = row0 + j;
        if (row < Mreal) {
          float v = acc[m][n][j];
          if constexpr (MODE == 1) Cb[row * NCOLS + col] = f2bf(fmaxf(v, 0.f));
          else if constexpr (MODE == 2) Cb[row * NCOLS + col] = f2bf(v);
          else if constexpr (MODE == 6) {
            if (col < 512)       Cb[row * 1024 + col] = f2h(v);
            else if (col < 1024) Cb2[row * 512 + (col - 512)] = f2h(v);
            else if (col < 1536) Cb[row * 1024 + 512 + (col - 1024)] = f2h(v);
            else                 Cb3[row * 512 + (col - 1536)] = f2bf(v);
          } else {  // MODE 7
            long o = row * NCOLS + col;
            Cf[o] = bf2f((u32)Cb2[o]) + v;
          }
        }
      }
    }
  }
}

// ---- single-pass scan: thread t serially scans 20 elems, 2 block barriers ----
__global__ __launch_bounds__(1024) void k_scan(const int* __restrict__ deg, int* __restrict__ offa)
{
  __shared__ int wsum[16];
  const int tid = threadIdx.x, lane = tid & 63, wid = tid >> 6;
  const int base = tid * 20;
  int loc[20];
  int s = 0;
#pragma unroll
  for (int j = 0; j < 20; j++) {
    int i = base + j;
    int v = (i < NN) ? deg[i] : 0;
    s += v; loc[j] = s;
  }
  int incl = s;
#pragma unroll
  for (int d = 1; d < 64; d <<= 1) { int t = __shfl_up(incl, d); if (lane >= d) incl += t; }
  if (lane == 63) wsum[wid] = incl;
  __syncthreads();
  if (tid < 16) {
    int ws = wsum[tid];
#pragma unroll
    for (int d = 1; d < 16; d <<= 1) { int t = __shfl_up(ws, d, 16); if (tid >= d) ws += t; }
    wsum[tid] = ws;
  }
  __syncthreads();
  int prev = incl - s + (wid ? wsum[wid - 1] : 0);
  if (tid == 0) offa[0] = 0;
#pragma unroll
  for (int j = 0; j < 20; j++) {
    int i = base + j;
    if (i < NN) offa[i + 1] = prev + loc[j];
  }
}

__global__ __launch_bounds__(256) void k_scatter(const int* __restrict__ src, const int* __restrict__ dst,
    const int* __restrict__ offa, int* __restrict__ cnt, int* __restrict__ esrcs)
{
  int e = blockIdx.x * 256 + threadIdx.x;
  if (e >= NE) return;
  int d = dst[e];
  int p = offa[d] + atomicAdd(&cnt[d], 1);
  esrcs[p] = src[e];
}

// ---- fused edge pass: 2 waves per dst node (4 heads each), 8-edge batches ----
// QV row: [q fp16 512 | v fp16 512]; Kb row: k fp16 512
__global__ __launch_bounds__(256) void k_edge(const int* __restrict__ offa,
    const int* __restrict__ esrcs, const u16* __restrict__ QV,
    const u16* __restrict__ Kb, u16* __restrict__ aggb)
{
  int wid = blockIdx.x * 4 + (threadIdx.x >> 6);
  int nd = wid >> 1, half = wid & 1;
  int lane = threadIdx.x & 63;
  if (nd >= MP) return;
  const int off = half * 256 + lane * 4;
  u16* op = aggb + (size_t)nd * FD + off;
  if (nd >= NN) { *(ushort4*)op = make_ushort4(0, 0, 0, 0); return; }
  uint2 kw = *(const uint2*)(Kb + (size_t)nd * 512 + off);
  float kx[4]; up_h4(kw, kx);
  int b0 = offa[nd], b1 = offa[nd + 1];
  float den = 0.f, a0 = 0.f, a1 = 0.f, a2 = 0.f, a3 = 0.f;
  for (int p = b0; p < b1; p += 8) {
    int ss[8]; uint2 qw[8], vw[8];
#pragma unroll
    for (int u = 0; u < 8; u++) { int ix = p + u; ss[u] = esrcs[ix < b1 ? ix : b1 - 1]; }
#pragma unroll
    for (int u = 0; u < 8; u++) {
      const u16* r = QV + (size_t)ss[u] * 1024 + off;
      qw[u] = *(const uint2*)r;
      vw[u] = *(const uint2*)(r + 512);
    }
#pragma unroll
    for (int u = 0; u < 8; u++) {
      float qx[4]; up_h4(qw[u], qx);
      float d = qx[0]*kx[0] + qx[1]*kx[1] + qx[2]*kx[2] + qx[3]*kx[3];
      d += __shfl_xor(d, 1); d += __shfl_xor(d, 2);
      d += __shfl_xor(d, 4); d += __shfl_xor(d, 8);
      float ex = __expf(fminf(fmaxf(d, -5.f), 5.f) * 8.f - 40.f);
      ex = (p + u < b1) ? ex : 0.f;
      den += ex;
      float vx[4]; up_h4(vw[u], vx);
      a0 += ex * vx[0]; a1 += ex * vx[1]; a2 += ex * vx[2]; a3 += ex * vx[3];
    }
  }
  float rd = 1.f / den;
  *(ushort4*)op = make_ushort4(f2bf(a0*rd), f2bf(a1*rd), f2bf(a2*rd), f2bf(a3*rd));
}

// ---- gate GEMV + gated residual + LN1 (-> h bf16) + LN2 (-> bf16) ----
__device__ __forceinline__ float blkred(float v, float* sb)
{
#pragma unroll
  for (int s = 1; s < 64; s <<= 1) v += __shfl_xor(v, s);
  __syncthreads();
  if ((threadIdx.x & 63) == 0) sb[threadIdx.x >> 6] = v;
  __syncthreads();
  return sb[0] + sb[1];
}

__global__ __launch_bounds__(128) void k_gate_ln(const u16* __restrict__ rstb, const u16* __restrict__ skpb,
    const float* __restrict__ gA, const float* __restrict__ gB,
    const float* __restrict__ g1, const float* __restrict__ b1,
    const float* __restrict__ g2, const float* __restrict__ b2,
    u16* __restrict__ hb, u16* __restrict__ h2b)
{
  __shared__ float sb[2];
  const int t = threadIdx.x;
  const size_t base = (size_t)blockIdx.x * FD + t * 4;
  ushort4 ru = *(const ushort4*)(rstb + base);
  ushort4 su = *(const ushort4*)(skpb + base);
  float r0 = bf2f(ru.x), r1 = bf2f(ru.y), r2 = bf2f(ru.z), r3 = bf2f(ru.w);
  float s0 = bf2f(su.x), s1 = bf2f(su.y), s2 = bf2f(su.z), s3 = bf2f(su.w);
  float4 av = *(const float4*)(gA + t * 4);
  float4 bv = *(const float4*)(gB + t * 4);
  float gd = r0*av.x + r1*av.y + r2*av.z + r3*av.w
           + s0*bv.x + s1*bv.y + s2*bv.z + s3*bv.w;
  float tot = blkred(gd, sb);
  float g = 1.f / (1.f + __expf(-tot));
  float x0 = g*r0 + (1.f-g)*s0;
  float x1 = g*r1 + (1.f-g)*s1;
  float x2 = g*r2 + (1.f-g)*s2;
  float x3 = g*r3 + (1.f-g)*s3;
  float m1 = blkred(x0+x1+x2+x3, sb) * (1.f/FD);
  float d0 = x0-m1, d1 = x1-m1, d2 = x2-m1, d3 = x3-m1;
  float v1 = blkred(d0*d0+d1*d1+d2*d2+d3*d3, sb) * (1.f/FD);
  float rs = rsqrtf(v1 + 1e-5f);
  float4 G1 = *(const float4*)(g1 + t*4);
  float4 Bb1 = *(const float4*)(b1 + t*4);
  float h0 = d0*rs*G1.x + Bb1.x;
  float h1 = d1*rs*G1.y + Bb1.y;
  float h2 = d2*rs*G1.z + Bb1.z;
  float h3 = d3*rs*G1.w + Bb1.w;
  *(ushort4*)(hb + base) = make_ushort4(f2bf(h0), f2bf(h1), f2bf(h2), f2bf(h3));
  float m2 = blkred(h0+h1+h2+h3, sb) * (1.f/FD);
  float e0 = h0-m2, e1 = h1-m2, e2 = h2-m2, e3 = h3-m2;
  float v2 = blkred(e0*e0+e1*e1+e2*e2+e3*e3, sb) * (1.f/FD);
  float rs2 = rsqrtf(v2 + 1e-5f);
  float4 G2 = *(const float4*)(g2 + t*4);
  float4 Bb2 = *(const float4*)(b2 + t*4);
  *(ushort4*)(h2b + base) = make_ushort4(
      f2bf(e0*rs2*G2.x + Bb2.x), f2bf(e1*rs2*G2.y + Bb2.y),
      f2bf(e2*rs2*G2.z + Bb2.z), f2bf(e3*rs2*G2.w + Bb2.w));
}

extern "C" void kernel_launch(void* const* d_in, const int* in_sizes, int n_in,
                              void* d_out, int out_size, void* d_ws, size_t ws_size,
                              hipStream_t stream)
{
  const float* feat = (const float*)d_in[0];
  const int* e_src = (const int*)d_in[1];
  const int* e_dst = (const int*)d_in[2];
  const float* Wq  = (const float*)d_in[3];
  const float* Wk  = (const float*)d_in[4];
  const float* Wv  = (const float*)d_in[5];
  const float* Wn  = (const float*)d_in[6];
  const float* Wsk = (const float*)d_in[7];
  const float* Wg  = (const float*)d_in[8];
  const float* l1g = (const float*)d_in[9];
  const float* l1b = (const float*)d_in[10];
  const float* l2g = (const float*)d_in[11];
  const float* l2b = (const float*)d_in[12];
  const float* W1  = (const float*)d_in[13];
  const float* W2  = (const float*)d_in[14];

  char* ws = (char*)d_ws;
  size_t o = 0;
  auto al = [&](size_t b) { char* r = ws + o; o = (o + b + 255) & ~(size_t)255; return r; };

  u16* Af    = (u16*)al((size_t)MP * FD * 2);      // feat fp16
  u16* Bqkvs = (u16*)al((size_t)2048 * FD * 2);    // [Wq|Wk|Wv|Wsk]^T fp16
  u16* Bnt   = (u16*)al((size_t)FD * FD * 2);
  u16* B1t   = (u16*)al((size_t)FD * FD * 2);
  u16* B2t   = (u16*)al((size_t)FD * FD * 2);
  float* gA  = (float*)al(FD * 4);
  float* gB  = (float*)al(FD * 4);
  u16* QV    = (u16*)al((size_t)MP * 1024 * 2);    // [q fp16 | v fp16] per node
  u16* Kb    = (u16*)al((size_t)MP * FD * 2);      // k fp16
  u16* SKIPb = (u16*)al((size_t)MP * FD * 2);      // bf16
  u16* aggb  = (u16*)al((size_t)MP * FD * 2);      // bf16
  u16* h2b   = (u16*)al((size_t)MP * FD * 2);      // bf16 (LN2 out)
  u16* hb    = (u16*)al((size_t)MP * FD * 2);      // bf16 (h, for W2 epilogue)
  int* deg   = (int*)al((size_t)2 * NN * 4);
  int* cnt   = deg + NN;
  int* offa  = (int*)al((size_t)(NN + 1) * 4);
  int* esrcs = (int*)al((size_t)NE * 4);
  if (o > ws_size) return;  // ~170 MB needed
  // aliases into dead regions
  u16* rstb = Kb;    // Kb dead after k_edge
  u16* midb = Af;    // Af dead after QKVS GEMM
  float* out = (float*)d_out;

  hipMemsetAsync(deg, 0, (size_t)2 * NN * 4, stream);

  {
    int total = MP * FD / 4 + 2048 * 512 + 3 * 512 * 512 + 512 + NE;
    k_wprep<<<dim3((total + 255) / 256), 256, 0, stream>>>(feat, Wq, Wk, Wv, Wsk, Wn, W1, W2, Wg,
        e_dst, Af, Bqkvs, Bnt, B1t, B2t, gA, gB, deg);
  }

  // one fp16 GEMM for Q,K,V,SKIP  [MP x 2048 x 512], 128x256 tile, XCD=row%8
  k_gemm<2048, 6, 1, 256><<<dim3(160, 8), 256, 0, stream>>>(Af, Bqkvs, nullptr, QV, Kb, SKIPb, MP);

  k_scan<<<dim3(1), 1024, 0, stream>>>(deg, offa);
  k_scatter<<<dim3((NE + 255) / 256), 256, 0, stream>>>(e_src, e_dst, offa, cnt, esrcs);
  k_edge<<<dim3(MP / 2), 256, 0, stream>>>(offa, esrcs, QV, Kb, aggb);

  k_gemm<512, 2, 0, 128><<<dim3(160, 4), 256, 0, stream>>>(aggb, Bnt, nullptr, rstb, nullptr, nullptr, MP);
  k_gate_ln<<<dim3(NN), 128, 0, stream>>>(rstb, SKIPb, gA, gB, l1g, l1b, l2g, l2b, hb, h2b);
  k_gemm<512, 1, 0, 128><<<dim3(160, 4), 256, 0, stream>>>(h2b, B1t, nullptr, midb, nullptr, nullptr, NN);
  k_gemm<512, 7, 0, 128><<<dim3(160, 4), 256, 0, stream>>>(midb, B2t, out, nullptr, hb, nullptr, NN);
}

// Round 9
// 317.341 us; speedup vs baseline: 1.4023x; 1.4023x over previous
//
#include <hip/hip_runtime.h>
#include <hip/hip_bf16.h>
#include <hip/hip_fp16.h>

#define NN 20000   // nodes
#define FD 512     // features
#define NH 8       // heads
#define NE 320000  // edges
#define MP 20096   // padded rows = 157*128

typedef unsigned int u32;
typedef unsigned short u16;
typedef __bf16 bf16x8 __attribute__((ext_vector_type(8)));
typedef _Float16 f16x8 __attribute__((ext_vector_type(8)));
typedef float f32x4 __attribute__((ext_vector_type(4)));

#define AS1 __attribute__((address_space(1)))
#define AS3 __attribute__((address_space(3)))

__device__ __forceinline__ u16 f2bf(float f) {
  __hip_bfloat16 h = __float2bfloat16(f);
  union { __hip_bfloat16 b; u16 u; } c; c.b = h; return c.u;
}
__device__ __forceinline__ float bf2f(u32 u) { return __uint_as_float(u << 16); }
__device__ __forceinline__ u16 f2h(float f) {
  union { __half h; u16 u; } c; c.h = __float2half(f); return c.u;
}
__device__ __forceinline__ void gl_lds16(const void* g, void* l) {
  __builtin_amdgcn_global_load_lds((AS1 void*)const_cast<void*>(g), (AS3 void*)l, 16, 0, 0);
}
__device__ __forceinline__ void up_h4(uint2 w, float* f) {
  union { u32 u; __half2 h; } c;
  c.u = w.x; float2 t0 = __half22float2(c.h); f[0]=t0.x; f[1]=t0.y;
  c.u = w.y; float2 t1 = __half22float2(c.h); f[2]=t1.x; f[3]=t1.y;
}

// ---- feat->fp16 + all weight prep + degree histogram in ONE kernel ----
__global__ __launch_bounds__(256) void k_wprep(const float* __restrict__ feat,
    const float* __restrict__ Wq, const float* __restrict__ Wk,
    const float* __restrict__ Wv, const float* __restrict__ Wsk,
    const float* __restrict__ Wn, const float* __restrict__ W1,
    const float* __restrict__ W2, const float* __restrict__ Wg,
    const int* __restrict__ e_dst,
    u16* __restrict__ Af, u16* __restrict__ Bqkvs, u16* __restrict__ Bnt,
    u16* __restrict__ B1t, u16* __restrict__ B2t,
    float* __restrict__ gA, float* __restrict__ gB, int* __restrict__ deg)
{
  int idx = blockIdx.x * 256 + threadIdx.x;
  if (idx < MP * FD / 4) {
    size_t i = (size_t)idx * 4;
    float4 v = make_float4(0.f, 0.f, 0.f, 0.f);
    if (i < (size_t)NN * FD) v = *(const float4*)(feat + i);
    *(ushort4*)(Af + i) = make_ushort4(f2h(v.x), f2h(v.y), f2h(v.z), f2h(v.w));
    return;
  }
  idx -= MP * FD / 4;
  if (idx < 2048 * 512) {
    int n = idx >> 9, k = idx & 511;
    float v;
    if (n < 512)       v = Wq[k * 512 + n];
    else if (n < 1024) v = Wk[k * 512 + (n - 512)];
    else if (n < 1536) v = Wv[k * 512 + (n - 1024)];
    else               v = Wsk[k * 512 + (n - 1536)];
    Bqkvs[idx] = f2h(v);
    return;
  }
  idx -= 2048 * 512;
  if (idx < 512 * 512) { int n = idx >> 9, k = idx & 511; Bnt[idx] = f2bf(Wn[k * 512 + n]); return; }
  idx -= 512 * 512;
  if (idx < 512 * 512) { int n = idx >> 9, k = idx & 511; B1t[idx] = f2bf(W1[k * 512 + n]); return; }
  idx -= 512 * 512;
  if (idx < 512 * 512) { int n = idx >> 9, k = idx & 511; B2t[idx] = f2bf(W2[k * 512 + n]); return; }
  idx -= 512 * 512;
  if (idx < 512) {
    gA[idx] = Wg[idx] + Wg[2 * 512 + idx];
    gB[idx] = Wg[512 + idx] - Wg[2 * 512 + idx];
    return;
  }
  idx -= 512;
  if (idx < NE) atomicAdd(&deg[e_dst[idx]], 1);
}

// ---- GEMM: A[M,512] x Bt[NCOLS,512] (both u16-encoded, FP16 or bf16) ----
// 128x128 tile, BK=32 double-buffer at 32 KB total LDS: 1 barrier/K-step,
// prefetch in flight across the MFMA phase, 4 blocks/CU.  acc[4][4]=64 VGPR
// (r8 lesson: 128x256 tile's acc[4][8]=128 VGPR spills under launch_bounds,
// turning the GEMM into a scratch-BW benchmark).  Grid.x padded to 160 so
// XCD = row%8 (A row-panel L2 affinity).
// MODE: 1=relu+bf16->Cb, 2=bf16->Cb,
//       6=QKVS split store: col<512 q->Cb(QV,stride1024 fp16); <1024 k->Cb2(fp16);
//                           <1536 v->Cb(QV+512 fp16); else skip->Cb3(bf16)
//       7=h+ffn: Cf[o] = bf2f(Cb2[o]) + v   (writes d_out once)
template<int NCOLS, int MODE, int FP16>
__global__ __launch_bounds__(256, 4) void k_gemm(
    const u16* __restrict__ A, const u16* __restrict__ B,
    float* __restrict__ Cf, u16* __restrict__ Cb, u16* __restrict__ Cb2,
    u16* __restrict__ Cb3, int Mreal)
{
  const long brow = (long)blockIdx.x * 128;
  if (brow >= MP) return;
  __shared__ u16 sA[2][128 * 32];
  __shared__ u16 sB[2][128 * 32];
  const int tid = threadIdx.x, lane = tid & 63, w = tid >> 6;
  const int wr = w >> 1, wc = w & 1;
  const long bcol = (long)blockIdx.y * 128;
  const int srl = tid >> 2, scl = (tid & 3) * 8;

  auto stage = [&](int b, int kt) {
#pragma unroll
    for (int s = 0; s < 2; s++) {
      gl_lds16(A + (brow + s * 64 + srl) * FD + kt + scl, &sA[b][s * 2048 + w * 512]);
      gl_lds16(B + (bcol + s * 64 + srl) * FD + kt + scl, &sB[b][s * 2048 + w * 512]);
    }
  };

  f32x4 acc[4][4] = {};
  stage(0, 0);
  __syncthreads();
  int cur = 0;
  const int ro = (lane >> 4) * 8;
  for (int kt = 0; kt < FD; kt += 32) {
    if (kt + 32 < FD) stage(cur ^ 1, kt + 32);
#pragma unroll
    for (int m = 0; m < 4; m++) {
      const u16* pa = &sA[cur][(wr * 64 + m * 16 + (lane & 15)) * 32 + ro];
#pragma unroll
      for (int n = 0; n < 4; n++) {
        const u16* pb = &sB[cur][(wc * 64 + n * 16 + (lane & 15)) * 32 + ro];
        if constexpr (FP16)
          acc[m][n] = __builtin_amdgcn_mfma_f32_16x16x32_f16(
              *(const f16x8*)pa, *(const f16x8*)pb, acc[m][n], 0, 0, 0);
        else
          acc[m][n] = __builtin_amdgcn_mfma_f32_16x16x32_bf16(
              *(const bf16x8*)pa, *(const bf16x8*)pb, acc[m][n], 0, 0, 0);
      }
    }
    __syncthreads();
    cur ^= 1;
  }
#pragma unroll
  for (int m = 0; m < 4; m++) {
    long row0 = brow + wr * 64 + m * 16 + (lane >> 4) * 4;
#pragma unroll
    for (int n = 0; n < 4; n++) {
      long col = bcol + wc * 64 + n * 16 + (lane & 15);
#pragma unroll
      for (int j = 0; j < 4; j++) {
        long row = row0 + j;
        if (row < Mreal) {
          float v = acc[m][n][j];
          if constexpr (MODE == 1) Cb[row * NCOLS + col] = f2bf(fmaxf(v, 0.f));
          else if constexpr (MODE == 2) Cb[row * NCOLS + col] = f2bf(v);
          else if constexpr (MODE == 6) {
            if (col < 512)       Cb[row * 1024 + col] = f2h(v);
            else if (col < 1024) Cb2[row * 512 + (col - 512)] = f2h(v);
            else if (col < 1536) Cb[row * 1024 + 512 + (col - 1024)] = f2h(v);
            else                 Cb3[row * 512 + (col - 1536)] = f2bf(v);
          } else {  // MODE 7
            long o = row * NCOLS + col;
            Cf[o] = bf2f((u32)Cb2[o]) + v;
          }
        }
      }
    }
  }
}

// ---- single-pass scan: thread t serially scans 20 elems, 2 block barriers ----
__global__ __launch_bounds__(1024) void k_scan(const int* __restrict__ deg, int* __restrict__ offa)
{
  __shared__ int wsum[16];
  const int tid = threadIdx.x, lane = tid & 63, wid = tid >> 6;
  const int base = tid * 20;
  int loc[20];
  int s = 0;
#pragma unroll
  for (int j = 0; j < 20; j++) {
    int i = base + j;
    int v = (i < NN) ? deg[i] : 0;
    s += v; loc[j] = s;
  }
  int incl = s;
#pragma unroll
  for (int d = 1; d < 64; d <<= 1) { int t = __shfl_up(incl, d); if (lane >= d) incl += t; }
  if (lane == 63) wsum[wid] = incl;
  __syncthreads();
  if (tid < 16) {
    int ws = wsum[tid];
#pragma unroll
    for (int d = 1; d < 16; d <<= 1) { int t = __shfl_up(ws, d, 16); if (tid >= d) ws += t; }
    wsum[tid] = ws;
  }
  __syncthreads();
  int prev = incl - s + (wid ? wsum[wid - 1] : 0);
  if (tid == 0) offa[0] = 0;
#pragma unroll
  for (int j = 0; j < 20; j++) {
    int i = base + j;
    if (i < NN) offa[i + 1] = prev + loc[j];
  }
}

__global__ __launch_bounds__(256) void k_scatter(const int* __restrict__ src, const int* __restrict__ dst,
    const int* __restrict__ offa, int* __restrict__ cnt, int* __restrict__ esrcs)
{
  int e = blockIdx.x * 256 + threadIdx.x;
  if (e >= NE) return;
  int d = dst[e];
  int p = offa[d] + atomicAdd(&cnt[d], 1);
  esrcs[p] = src[e];
}

// ---- fused edge pass: 2 waves per dst node (4 heads each), 8-edge batches ----
// QV row: [q fp16 512 | v fp16 512]; Kb row: k fp16 512
__global__ __launch_bounds__(256) void k_edge(const int* __restrict__ offa,
    const int* __restrict__ esrcs, const u16* __restrict__ QV,
    const u16* __restrict__ Kb, u16* __restrict__ aggb)
{
  int wid = blockIdx.x * 4 + (threadIdx.x >> 6);
  int nd = wid >> 1, half = wid & 1;
  int lane = threadIdx.x & 63;
  if (nd >= MP) return;
  const int off = half * 256 + lane * 4;
  u16* op = aggb + (size_t)nd * FD + off;
  if (nd >= NN) { *(ushort4*)op = make_ushort4(0, 0, 0, 0); return; }
  uint2 kw = *(const uint2*)(Kb + (size_t)nd * 512 + off);
  float kx[4]; up_h4(kw, kx);
  int b0 = offa[nd], b1 = offa[nd + 1];
  float den = 0.f, a0 = 0.f, a1 = 0.f, a2 = 0.f, a3 = 0.f;
  for (int p = b0; p < b1; p += 8) {
    int ss[8]; uint2 qw[8], vw[8];
#pragma unroll
    for (int u = 0; u < 8; u++) { int ix = p + u; ss[u] = esrcs[ix < b1 ? ix : b1 - 1]; }
#pragma unroll
    for (int u = 0; u < 8; u++) {
      const u16* r = QV + (size_t)ss[u] * 1024 + off;
      qw[u] = *(const uint2*)r;
      vw[u] = *(const uint2*)(r + 512);
    }
#pragma unroll
    for (int u = 0; u < 8; u++) {
      float qx[4]; up_h4(qw[u], qx);
      float d = qx[0]*kx[0] + qx[1]*kx[1] + qx[2]*kx[2] + qx[3]*kx[3];
      d += __shfl_xor(d, 1); d += __shfl_xor(d, 2);
      d += __shfl_xor(d, 4); d += __shfl_xor(d, 8);
      float ex = __expf(fminf(fmaxf(d, -5.f), 5.f) * 8.f - 40.f);
      ex = (p + u < b1) ? ex : 0.f;
      den += ex;
      float vx[4]; up_h4(vw[u], vx);
      a0 += ex * vx[0]; a1 += ex * vx[1]; a2 += ex * vx[2]; a3 += ex * vx[3];
    }
  }
  float rd = 1.f / den;
  *(ushort4*)op = make_ushort4(f2bf(a0*rd), f2bf(a1*rd), f2bf(a2*rd), f2bf(a3*rd));
}

// ---- gate GEMV + gated residual + LN1 (-> h bf16) + LN2 (-> bf16) ----
__device__ __forceinline__ float blkred(float v, float* sb)
{
#pragma unroll
  for (int s = 1; s < 64; s <<= 1) v += __shfl_xor(v, s);
  __syncthreads();
  if ((threadIdx.x & 63) == 0) sb[threadIdx.x >> 6] = v;
  __syncthreads();
  return sb[0] + sb[1];
}

__global__ __launch_bounds__(128) void k_gate_ln(const u16* __restrict__ rstb, const u16* __restrict__ skpb,
    const float* __restrict__ gA, const float* __restrict__ gB,
    const float* __restrict__ g1, const float* __restrict__ b1,
    const float* __restrict__ g2, const float* __restrict__ b2,
    u16* __restrict__ hb, u16* __restrict__ h2b)
{
  __shared__ float sb[2];
  const int t = threadIdx.x;
  const size_t base = (size_t)blockIdx.x * FD + t * 4;
  ushort4 ru = *(const ushort4*)(rstb + base);
  ushort4 su = *(const ushort4*)(skpb + base);
  float r0 = bf2f(ru.x), r1 = bf2f(ru.y), r2 = bf2f(ru.z), r3 = bf2f(ru.w);
  float s0 = bf2f(su.x), s1 = bf2f(su.y), s2 = bf2f(su.z), s3 = bf2f(su.w);
  float4 av = *(const float4*)(gA + t * 4);
  float4 bv = *(const float4*)(gB + t * 4);
  float gd = r0*av.x + r1*av.y + r2*av.z + r3*av.w
           + s0*bv.x + s1*bv.y + s2*bv.z + s3*bv.w;
  float tot = blkred(gd, sb);
  float g = 1.f / (1.f + __expf(-tot));
  float x0 = g*r0 + (1.f-g)*s0;
  float x1 = g*r1 + (1.f-g)*s1;
  float x2 = g*r2 + (1.f-g)*s2;
  float x3 = g*r3 + (1.f-g)*s3;
  float m1 = blkred(x0+x1+x2+x3, sb) * (1.f/FD);
  float d0 = x0-m1, d1 = x1-m1, d2 = x2-m1, d3 = x3-m1;
  float v1 = blkred(d0*d0+d1*d1+d2*d2+d3*d3, sb) * (1.f/FD);
  float rs = rsqrtf(v1 + 1e-5f);
  float4 G1 = *(const float4*)(g1 + t*4);
  float4 Bb1 = *(const float4*)(b1 + t*4);
  float h0 = d0*rs*G1.x + Bb1.x;
  float h1 = d1*rs*G1.y + Bb1.y;
  float h2 = d2*rs*G1.z + Bb1.z;
  float h3 = d3*rs*G1.w + Bb1.w;
  *(ushort4*)(hb + base) = make_ushort4(f2bf(h0), f2bf(h1), f2bf(h2), f2bf(h3));
  float m2 = blkred(h0+h1+h2+h3, sb) * (1.f/FD);
  float e0 = h0-m2, e1 = h1-m2, e2 = h2-m2, e3 = h3-m2;
  float v2 = blkred(e0*e0+e1*e1+e2*e2+e3*e3, sb) * (1.f/FD);
  float rs2 = rsqrtf(v2 + 1e-5f);
  float4 G2 = *(const float4*)(g2 + t*4);
  float4 Bb2 = *(const float4*)(b2 + t*4);
  *(ushort4*)(h2b + base) = make_ushort4(
      f2bf(e0*rs2*G2.x + Bb2.x), f2bf(e1*rs2*G2.y + Bb2.y),
      f2bf(e2*rs2*G2.z + Bb2.z), f2bf(e3*rs2*G2.w + Bb2.w));
}

extern "C" void kernel_launch(void* const* d_in, const int* in_sizes, int n_in,
                              void* d_out, int out_size, void* d_ws, size_t ws_size,
                              hipStream_t stream)
{
  const float* feat = (const float*)d_in[0];
  const int* e_src = (const int*)d_in[1];
  const int* e_dst = (const int*)d_in[2];
  const float* Wq  = (const float*)d_in[3];
  const float* Wk  = (const float*)d_in[4];
  const float* Wv  = (const float*)d_in[5];
  const float* Wn  = (const float*)d_in[6];
  const float* Wsk = (const float*)d_in[7];
  const float* Wg  = (const float*)d_in[8];
  const float* l1g = (const float*)d_in[9];
  const float* l1b = (const float*)d_in[10];
  const float* l2g = (const float*)d_in[11];
  const float* l2b = (const float*)d_in[12];
  const float* W1  = (const float*)d_in[13];
  const float* W2  = (const float*)d_in[14];

  char* ws = (char*)d_ws;
  size_t o = 0;
  auto al = [&](size_t b) { char* r = ws + o; o = (o + b + 255) & ~(size_t)255; return r; };

  u16* Af    = (u16*)al((size_t)MP * FD * 2);      // feat fp16
  u16* Bqkvs = (u16*)al((size_t)2048 * FD * 2);    // [Wq|Wk|Wv|Wsk]^T fp16
  u16* Bnt   = (u16*)al((size_t)FD * FD * 2);
  u16* B1t   = (u16*)al((size_t)FD * FD * 2);
  u16* B2t   = (u16*)al((size_t)FD * FD * 2);
  float* gA  = (float*)al(FD * 4);
  float* gB  = (float*)al(FD * 4);
  u16* QV    = (u16*)al((size_t)MP * 1024 * 2);    // [q fp16 | v fp16] per node
  u16* Kb    = (u16*)al((size_t)MP * FD * 2);      // k fp16
  u16* SKIPb = (u16*)al((size_t)MP * FD * 2);      // bf16
  u16* aggb  = (u16*)al((size_t)MP * FD * 2);      // bf16
  u16* h2b   = (u16*)al((size_t)MP * FD * 2);      // bf16 (LN2 out)
  u16* hb    = (u16*)al((size_t)MP * FD * 2);      // bf16 (h, for W2 epilogue)
  int* deg   = (int*)al((size_t)2 * NN * 4);
  int* cnt   = deg + NN;
  int* offa  = (int*)al((size_t)(NN + 1) * 4);
  int* esrcs = (int*)al((size_t)NE * 4);
  if (o > ws_size) return;  // ~170 MB needed
  // aliases into dead regions
  u16* rstb = Kb;    // Kb dead after k_edge
  u16* midb = Af;    // Af dead after QKVS GEMM
  float* out = (float*)d_out;

  hipMemsetAsync(deg, 0, (size_t)2 * NN * 4, stream);

  {
    int total = MP * FD / 4 + 2048 * 512 + 3 * 512 * 512 + 512 + NE;
    k_wprep<<<dim3((total + 255) / 256), 256, 0, stream>>>(feat, Wq, Wk, Wv, Wsk, Wn, W1, W2, Wg,
        e_dst, Af, Bqkvs, Bnt, B1t, B2t, gA, gB, deg);
  }

  // one fp16 GEMM for Q,K,V,SKIP  [MP x 2048 x 512], 128x128 tile, XCD=row%8
  k_gemm<2048, 6, 1><<<dim3(160, 16), 256, 0, stream>>>(Af, Bqkvs, nullptr, QV, Kb, SKIPb, MP);

  k_scan<<<dim3(1), 1024, 0, stream>>>(deg, offa);
  k_scatter<<<dim3((NE + 255) / 256), 256, 0, stream>>>(e_src, e_dst, offa, cnt, esrcs);
  k_edge<<<dim3(MP / 2), 256, 0, stream>>>(offa, esrcs, QV, Kb, aggb);

  k_gemm<512, 2, 0><<<dim3(160, 4), 256, 0, stream>>>(aggb, Bnt, nullptr, rstb, nullptr, nullptr, MP);
  k_gate_ln<<<dim3(NN), 128, 0, stream>>>(rstb, SKIPb, gA, gB, l1g, l1b, l2g, l2b, hb, h2b);
  k_gemm<512, 1, 0><<<dim3(160, 4), 256, 0, stream>>>(h2b, B1t, nullptr, midb, nullptr, nullptr, NN);
  k_gemm<512, 7, 0><<<dim3(160, 4), 256, 0, stream>>>(midb, B2t, out, nullptr, hb, nullptr, NN);
}

// Round 10
// 315.654 us; speedup vs baseline: 1.4098x; 1.0053x over previous
//
#include <hip/hip_runtime.h>
#include <hip/hip_bf16.h>
#include <hip/hip_fp16.h>

#define NN 20000   // nodes
#define FD 512     // features
#define NH 8       // heads
#define NE 320000  // edges
#define MP 20096   // padded rows = 157*128

typedef unsigned int u32;
typedef unsigned short u16;
typedef __bf16 bf16x8 __attribute__((ext_vector_type(8)));
typedef _Float16 f16x8 __attribute__((ext_vector_type(8)));
typedef float f32x4 __attribute__((ext_vector_type(4)));

#define AS1 __attribute__((address_space(1)))
#define AS3 __attribute__((address_space(3)))

__device__ __forceinline__ u16 f2bf(float f) {
  __hip_bfloat16 h = __float2bfloat16(f);
  union { __hip_bfloat16 b; u16 u; } c; c.b = h; return c.u;
}
__device__ __forceinline__ float bf2f(u32 u) { return __uint_as_float(u << 16); }
__device__ __forceinline__ u16 f2h(float f) {
  union { __half h; u16 u; } c; c.h = __float2half(f); return c.u;
}
__device__ __forceinline__ void gl_lds16(const void* g, void* l) {
  __builtin_amdgcn_global_load_lds((AS1 void*)const_cast<void*>(g), (AS3 void*)l, 16, 0, 0);
}
__device__ __forceinline__ void up_h4(uint2 w, float* f) {
  union { u32 u; __half2 h; } c;
  c.u = w.x; float2 t0 = __half22float2(c.h); f[0]=t0.x; f[1]=t0.y;
  c.u = w.y; float2 t1 = __half22float2(c.h); f[2]=t1.x; f[3]=t1.y;
}

// ---- feat->fp16 + all weight prep + degree histogram in ONE kernel ----
// Bqkvs col n (0..2047), pre-permuted so GEMM MODE6 stores are linear:
//   n<1024:  group g=n>>3, j=n&7: j<4 -> Wq dim 4g+(j&3), else Wv dim 4g+(j&3)
//            => QV row is [q0..q3 v0..v3 | q4..q7 v4..v7 | ...] (16B per 4-dim group)
//   n<1536:  Wk col n-1024 -> Kb ;  else Wsk col n-1536 -> SKIPb
__global__ __launch_bounds__(256) void k_wprep(const float* __restrict__ feat,
    const float* __restrict__ Wq, const float* __restrict__ Wk,
    const float* __restrict__ Wv, const float* __restrict__ Wsk,
    const float* __restrict__ Wn, const float* __restrict__ W1,
    const float* __restrict__ W2, const float* __restrict__ Wg,
    const int* __restrict__ e_dst,
    u16* __restrict__ Af, u16* __restrict__ Bqkvs, u16* __restrict__ Bnt,
    u16* __restrict__ B1t, u16* __restrict__ B2t,
    float* __restrict__ gA, float* __restrict__ gB, int* __restrict__ deg)
{
  int idx = blockIdx.x * 256 + threadIdx.x;
  if (idx < MP * FD / 4) {
    size_t i = (size_t)idx * 4;
    float4 v = make_float4(0.f, 0.f, 0.f, 0.f);
    if (i < (size_t)NN * FD) v = *(const float4*)(feat + i);
    *(ushort4*)(Af + i) = make_ushort4(f2h(v.x), f2h(v.y), f2h(v.z), f2h(v.w));
    return;
  }
  idx -= MP * FD / 4;
  if (idx < 2048 * 512) {
    int n = idx >> 9, k = idx & 511;
    float v;
    if (n < 1024) {
      int j = n & 7, dim = (n >> 3) * 4 + (j & 3);
      v = (j < 4) ? Wq[k * 512 + dim] : Wv[k * 512 + dim];
    } else if (n < 1536) v = Wk[k * 512 + (n - 1024)];
    else                 v = Wsk[k * 512 + (n - 1536)];
    Bqkvs[idx] = f2h(v);
    return;
  }
  idx -= 2048 * 512;
  if (idx < 512 * 512) { int n = idx >> 9, k = idx & 511; Bnt[idx] = f2bf(Wn[k * 512 + n]); return; }
  idx -= 512 * 512;
  if (idx < 512 * 512) { int n = idx >> 9, k = idx & 511; B1t[idx] = f2bf(W1[k * 512 + n]); return; }
  idx -= 512 * 512;
  if (idx < 512 * 512) { int n = idx >> 9, k = idx & 511; B2t[idx] = f2bf(W2[k * 512 + n]); return; }
  idx -= 512 * 512;
  if (idx < 512) {
    gA[idx] = Wg[idx] + Wg[2 * 512 + idx];
    gB[idx] = Wg[512 + idx] - Wg[2 * 512 + idx];
    return;
  }
  idx -= 512;
  if (idx < NE) atomicAdd(&deg[e_dst[idx]], 1);
}

// ---- GEMM: A[M,512] x Bt[NCOLS,512] (both u16-encoded, FP16 or bf16) ----
// 128x128 tile, BK=32 double-buffer at 32 KB LDS, 4 blocks/CU, XCD=row%8.
// MODE: 1=relu+bf16->Cb, 2=bf16->Cb,
//       6=QKVS split store: col<1024 -> Cb=QV (interleaved q|v, fp16, linear);
//                           col<1536 -> Cb2=Kb fp16; else Cb3=SKIPb bf16
//       7=h+ffn: Cf[o] = bf2f(Cb2[o]) + v   (writes d_out once)
template<int NCOLS, int MODE, int FP16>
__global__ __launch_bounds__(256, 4) void k_gemm(
    const u16* __restrict__ A, const u16* __restrict__ B,
    float* __restrict__ Cf, u16* __restrict__ Cb, u16* __restrict__ Cb2,
    u16* __restrict__ Cb3, int Mreal)
{
  const long brow = (long)blockIdx.x * 128;
  if (brow >= MP) return;
  __shared__ u16 sA[2][128 * 32];
  __shared__ u16 sB[2][128 * 32];
  const int tid = threadIdx.x, lane = tid & 63, w = tid >> 6;
  const int wr = w >> 1, wc = w & 1;
  const long bcol = (long)blockIdx.y * 128;
  const int srl = tid >> 2, scl = (tid & 3) * 8;

  auto stage = [&](int b, int kt) {
#pragma unroll
    for (int s = 0; s < 2; s++) {
      gl_lds16(A + (brow + s * 64 + srl) * FD + kt + scl, &sA[b][s * 2048 + w * 512]);
      gl_lds16(B + (bcol + s * 64 + srl) * FD + kt + scl, &sB[b][s * 2048 + w * 512]);
    }
  };

  f32x4 acc[4][4] = {};
  stage(0, 0);
  __syncthreads();
  int cur = 0;
  const int ro = (lane >> 4) * 8;
  for (int kt = 0; kt < FD; kt += 32) {
    if (kt + 32 < FD) stage(cur ^ 1, kt + 32);
#pragma unroll
    for (int m = 0; m < 4; m++) {
      const u16* pa = &sA[cur][(wr * 64 + m * 16 + (lane & 15)) * 32 + ro];
#pragma unroll
      for (int n = 0; n < 4; n++) {
        const u16* pb = &sB[cur][(wc * 64 + n * 16 + (lane & 15)) * 32 + ro];
        if constexpr (FP16)
          acc[m][n] = __builtin_amdgcn_mfma_f32_16x16x32_f16(
              *(const f16x8*)pa, *(const f16x8*)pb, acc[m][n], 0, 0, 0);
        else
          acc[m][n] = __builtin_amdgcn_mfma_f32_16x16x32_bf16(
              *(const bf16x8*)pa, *(const bf16x8*)pb, acc[m][n], 0, 0, 0);
      }
    }
    __syncthreads();
    cur ^= 1;
  }
#pragma unroll
  for (int m = 0; m < 4; m++) {
    long row0 = brow + wr * 64 + m * 16 + (lane >> 4) * 4;
#pragma unroll
    for (int n = 0; n < 4; n++) {
      long col = bcol + wc * 64 + n * 16 + (lane & 15);
#pragma unroll
      for (int j = 0; j < 4; j++) {
        long row = row0 + j;
        if (row < Mreal) {
          float v = acc[m][n][j];
          if constexpr (MODE == 1) Cb[row * NCOLS + col] = f2bf(fmaxf(v, 0.f));
          else if constexpr (MODE == 2) Cb[row * NCOLS + col] = f2bf(v);
          else if constexpr (MODE == 6) {
            if (col < 1024)      Cb[row * 1024 + col] = f2h(v);
            else if (col < 1536) Cb2[row * 512 + (col - 1024)] = f2h(v);
            else                 Cb3[row * 512 + (col - 1536)] = f2bf(v);
          } else {  // MODE 7
            long o = row * NCOLS + col;
            Cf[o] = bf2f((u32)Cb2[o]) + v;
          }
        }
      }
    }
  }
}

// ---- single-pass scan: thread t serially scans 20 elems, 2 block barriers ----
__global__ __launch_bounds__(1024) void k_scan(const int* __restrict__ deg, int* __restrict__ offa)
{
  __shared__ int wsum[16];
  const int tid = threadIdx.x, lane = tid & 63, wid = tid >> 6;
  const int base = tid * 20;
  int loc[20];
  int s = 0;
#pragma unroll
  for (int j = 0; j < 20; j++) {
    int i = base + j;
    int v = (i < NN) ? deg[i] : 0;
    s += v; loc[j] = s;
  }
  int incl = s;
#pragma unroll
  for (int d = 1; d < 64; d <<= 1) { int t = __shfl_up(incl, d); if (lane >= d) incl += t; }
  if (lane == 63) wsum[wid] = incl;
  __syncthreads();
  if (tid < 16) {
    int ws = wsum[tid];
#pragma unroll
    for (int d = 1; d < 16; d <<= 1) { int t = __shfl_up(ws, d, 16); if (tid >= d) ws += t; }
    wsum[tid] = ws;
  }
  __syncthreads();
  int prev = incl - s + (wid ? wsum[wid - 1] : 0);
  if (tid == 0) offa[0] = 0;
#pragma unroll
  for (int j = 0; j < 20; j++) {
    int i = base + j;
    if (i < NN) offa[i + 1] = prev + loc[j];
  }
}

__global__ __launch_bounds__(256) void k_scatter(const int* __restrict__ src, const int* __restrict__ dst,
    const int* __restrict__ offa, int* __restrict__ cnt, int* __restrict__ esrcs)
{
  int e = blockIdx.x * 256 + threadIdx.x;
  if (e >= NE) return;
  int d = dst[e];
  int p = offa[d] + atomicAdd(&cnt[d], 1);
  esrcs[p] = src[e];
}

// ---- fused edge pass: 2 waves per dst node (4 heads each), 8-edge batches ----
// QV row (interleaved): group g holds [q[4g..4g+3] | v[4g..4g+3]] fp16 (16B).
// One uint4 load per lane per edge == one contiguous 1KB segment per wave.
__global__ __launch_bounds__(256) void k_edge(const int* __restrict__ offa,
    const int* __restrict__ esrcs, const u16* __restrict__ QV,
    const u16* __restrict__ Kb, u16* __restrict__ aggb)
{
  int wid = blockIdx.x * 4 + (threadIdx.x >> 6);
  int nd = wid >> 1, half = wid & 1;
  int lane = threadIdx.x & 63;
  if (nd >= MP) return;
  const int g = half * 64 + lane;          // 4-dim group index, dims [4g,4g+4)
  u16* op = aggb + (size_t)nd * FD + g * 4;
  if (nd >= NN) { *(ushort4*)op = make_ushort4(0, 0, 0, 0); return; }
  uint2 kw = *(const uint2*)(Kb + (size_t)nd * 512 + g * 4);
  float kx[4]; up_h4(kw, kx);
  int b0 = offa[nd], b1 = offa[nd + 1];
  float den = 0.f, a0 = 0.f, a1 = 0.f, a2 = 0.f, a3 = 0.f;
  for (int p = b0; p < b1; p += 8) {
    int ss[8]; uint4 qv[8];
#pragma unroll
    for (int u = 0; u < 8; u++) { int ix = p + u; ss[u] = esrcs[ix < b1 ? ix : b1 - 1]; }
#pragma unroll
    for (int u = 0; u < 8; u++)
      qv[u] = *(const uint4*)(QV + (size_t)ss[u] * 1024 + g * 8);
#pragma unroll
    for (int u = 0; u < 8; u++) {
      float qx[4]; up_h4(make_uint2(qv[u].x, qv[u].y), qx);
      float d = qx[0]*kx[0] + qx[1]*kx[1] + qx[2]*kx[2] + qx[3]*kx[3];
      d += __shfl_xor(d, 1); d += __shfl_xor(d, 2);
      d += __shfl_xor(d, 4); d += __shfl_xor(d, 8);
      float ex = __expf(fminf(fmaxf(d, -5.f), 5.f) * 8.f - 40.f);
      ex = (p + u < b1) ? ex : 0.f;
      den += ex;
      float vx[4]; up_h4(make_uint2(qv[u].z, qv[u].w), vx);
      a0 += ex * vx[0]; a1 += ex * vx[1]; a2 += ex * vx[2]; a3 += ex * vx[3];
    }
  }
  float rd = 1.f / den;
  *(ushort4*)op = make_ushort4(f2bf(a0*rd), f2bf(a1*rd), f2bf(a2*rd), f2bf(a3*rd));
}

// ---- gate GEMV + gated residual + LN1 (-> h bf16) + LN2 (-> bf16) ----
__device__ __forceinline__ float blkred(float v, float* sb)
{
#pragma unroll
  for (int s = 1; s < 64; s <<= 1) v += __shfl_xor(v, s);
  __syncthreads();
  if ((threadIdx.x & 63) == 0) sb[threadIdx.x >> 6] = v;
  __syncthreads();
  return sb[0] + sb[1];
}

__global__ __launch_bounds__(128) void k_gate_ln(const u16* __restrict__ rstb, const u16* __restrict__ skpb,
    const float* __restrict__ gA, const float* __restrict__ gB,
    const float* __restrict__ g1, const float* __restrict__ b1,
    const float* __restrict__ g2, const float* __restrict__ b2,
    u16* __restrict__ hb, u16* __restrict__ h2b)
{
  __shared__ float sb[2];
  const int t = threadIdx.x;
  const size_t base = (size_t)blockIdx.x * FD + t * 4;
  ushort4 ru = *(const ushort4*)(rstb + base);
  ushort4 su = *(const ushort4*)(skpb + base);
  float r0 = bf2f(ru.x), r1 = bf2f(ru.y), r2 = bf2f(ru.z), r3 = bf2f(ru.w);
  float s0 = bf2f(su.x), s1 = bf2f(su.y), s2 = bf2f(su.z), s3 = bf2f(su.w);
  float4 av = *(const float4*)(gA + t * 4);
  float4 bv = *(const float4*)(gB + t * 4);
  float gd = r0*av.x + r1*av.y + r2*av.z + r3*av.w
           + s0*bv.x + s1*bv.y + s2*bv.z + s3*bv.w;
  float tot = blkred(gd, sb);
  float g = 1.f / (1.f + __expf(-tot));
  float x0 = g*r0 + (1.f-g)*s0;
  float x1 = g*r1 + (1.f-g)*s1;
  float x2 = g*r2 + (1.f-g)*s2;
  float x3 = g*r3 + (1.f-g)*s3;
  float m1 = blkred(x0+x1+x2+x3, sb) * (1.f/FD);
  float d0 = x0-m1, d1 = x1-m1, d2 = x2-m1, d3 = x3-m1;
  float v1 = blkred(d0*d0+d1*d1+d2*d2+d3*d3, sb) * (1.f/FD);
  float rs = rsqrtf(v1 + 1e-5f);
  float4 G1 = *(const float4*)(g1 + t*4);
  float4 Bb1 = *(const float4*)(b1 + t*4);
  float h0 = d0*rs*G1.x + Bb1.x;
  float h1 = d1*rs*G1.y + Bb1.y;
  float h2 = d2*rs*G1.z + Bb1.z;
  float h3 = d3*rs*G1.w + Bb1.w;
  *(ushort4*)(hb + base) = make_ushort4(f2bf(h0), f2bf(h1), f2bf(h2), f2bf(h3));
  float m2 = blkred(h0+h1+h2+h3, sb) * (1.f/FD);
  float e0 = h0-m2, e1 = h1-m2, e2 = h2-m2, e3 = h3-m2;
  float v2 = blkred(e0*e0+e1*e1+e2*e2+e3*e3, sb) * (1.f/FD);
  float rs2 = rsqrtf(v2 + 1e-5f);
  float4 G2 = *(const float4*)(g2 + t*4);
  float4 Bb2 = *(const float4*)(b2 + t*4);
  *(ushort4*)(h2b + base) = make_ushort4(
      f2bf(e0*rs2*G2.x + Bb2.x), f2bf(e1*rs2*G2.y + Bb2.y),
      f2bf(e2*rs2*G2.z + Bb2.z), f2bf(e3*rs2*G2.w + Bb2.w));
}

extern "C" void kernel_launch(void* const* d_in, const int* in_sizes, int n_in,
                              void* d_out, int out_size, void* d_ws, size_t ws_size,
                              hipStream_t stream)
{
  const float* feat = (const float*)d_in[0];
  const int* e_src = (const int*)d_in[1];
  const int* e_dst = (const int*)d_in[2];
  const float* Wq  = (const float*)d_in[3];
  const float* Wk  = (const float*)d_in[4];
  const float* Wv  = (const float*)d_in[5];
  const float* Wn  = (const float*)d_in[6];
  const float* Wsk = (const float*)d_in[7];
  const float* Wg  = (const float*)d_in[8];
  const float* l1g = (const float*)d_in[9];
  const float* l1b = (const float*)d_in[10];
  const float* l2g = (const float*)d_in[11];
  const float* l2b = (const float*)d_in[12];
  const float* W1  = (const float*)d_in[13];
  const float* W2  = (const float*)d_in[14];

  char* ws = (char*)d_ws;
  size_t o = 0;
  auto al = [&](size_t b) { char* r = ws + o; o = (o + b + 255) & ~(size_t)255; return r; };

  u16* Af    = (u16*)al((size_t)MP * FD * 2);      // feat fp16
  u16* Bqkvs = (u16*)al((size_t)2048 * FD * 2);    // permuted [q|v interleave, K, SKIP]^T fp16
  u16* Bnt   = (u16*)al((size_t)FD * FD * 2);
  u16* B1t   = (u16*)al((size_t)FD * FD * 2);
  u16* B2t   = (u16*)al((size_t)FD * FD * 2);
  float* gA  = (float*)al(FD * 4);
  float* gB  = (float*)al(FD * 4);
  u16* QV    = (u16*)al((size_t)MP * 1024 * 2);    // interleaved [q|v] fp16 per node
  u16* Kb    = (u16*)al((size_t)MP * FD * 2);      // k fp16
  u16* SKIPb = (u16*)al((size_t)MP * FD * 2);      // bf16
  u16* aggb  = (u16*)al((size_t)MP * FD * 2);      // bf16
  u16* h2b   = (u16*)al((size_t)MP * FD * 2);      // bf16 (LN2 out)
  u16* hb    = (u16*)al((size_t)MP * FD * 2);      // bf16 (h, for W2 epilogue)
  int* deg   = (int*)al((size_t)2 * NN * 4);
  int* cnt   = deg + NN;
  int* offa  = (int*)al((size_t)(NN + 1) * 4);
  int* esrcs = (int*)al((size_t)NE * 4);
  if (o > ws_size) return;  // ~170 MB needed
  // aliases into dead regions
  u16* rstb = Kb;    // Kb dead after k_edge
  u16* midb = Af;    // Af dead after QKVS GEMM
  float* out = (float*)d_out;

  hipMemsetAsync(deg, 0, (size_t)2 * NN * 4, stream);

  {
    int total = MP * FD / 4 + 2048 * 512 + 3 * 512 * 512 + 512 + NE;
    k_wprep<<<dim3((total + 255) / 256), 256, 0, stream>>>(feat, Wq, Wk, Wv, Wsk, Wn, W1, W2, Wg,
        e_dst, Af, Bqkvs, Bnt, B1t, B2t, gA, gB, deg);
  }

  // one fp16 GEMM for Q,K,V,SKIP  [MP x 2048 x 512], 128x128 tile, XCD=row%8
  k_gemm<2048, 6, 1><<<dim3(160, 16), 256, 0, stream>>>(Af, Bqkvs, nullptr, QV, Kb, SKIPb, MP);

  k_scan<<<dim3(1), 1024, 0, stream>>>(deg, offa);
  k_scatter<<<dim3((NE + 255) / 256), 256, 0, stream>>>(e_src, e_dst, offa, cnt, esrcs);
  k_edge<<<dim3(MP / 2), 256, 0, stream>>>(offa, esrcs, QV, Kb, aggb);

  k_gemm<512, 2, 0><<<dim3(160, 4), 256, 0, stream>>>(aggb, Bnt, nullptr, rstb, nullptr, nullptr, MP);
  k_gate_ln<<<dim3(NN), 128, 0, stream>>>(rstb, SKIPb, gA, gB, l1g, l1b, l2g, l2b, hb, h2b);
  k_gemm<512, 1, 0><<<dim3(160, 4), 256, 0, stream>>>(h2b, B1t, nullptr, midb, nullptr, nullptr, NN);
  k_gemm<512, 7, 0><<<dim3(160, 4), 256, 0, stream>>>(midb, B2t, out, nullptr, hb, nullptr, NN);
}